// Round 1
// baseline (264.603 us; speedup 1.0000x reference)
//
#include <hip/hip_runtime.h>
#include <math.h>

// Problem constants (from reference): B=8, N_INST=64, H=W=480
#define HW      (480 * 480)     // 230400 pixels per plane
#define HW4     (HW / 4)        // 57600 float4 per plane
#define NINST   64
#define BPI     32              // blocks per instance
#define NV      9               // reduced values: mask, q0..3, s0..2, z
#define THREADS 256

// Fused kernel: for instance n (block group), stream its pixels once:
//  - write xy_masked = mask * xy[sid]
//  - accumulate mask_sum, sum(mask*q_c), sum(mask*s_c), sum(mask*z)
// Partial sums per block -> part[block][NV]  (deterministic two-stage reduce)
__global__ __launch_bounds__(THREADS) void agg_main(
    const float* __restrict__ masks,   // [N,H,W]
    const int*   __restrict__ sids,    // [N]
    const float* __restrict__ quat,    // [B,4,H,W]
    const float* __restrict__ scales,  // [B,3,H,W]
    const float* __restrict__ xy,      // [B,2,H,W]
    const float* __restrict__ z,       // [B,H,W]
    float*       __restrict__ out,     // xy_masked lives at out+512
    float*       __restrict__ part)    // [NINST*BPI][NV]
{
    const int blk = blockIdx.x;
    const int n   = blk >> 5;          // instance (BPI = 32)
    const int b   = blk & (BPI - 1);
    const int tid = threadIdx.x;
    const int sid = sids[n];

    const float4* m4  = (const float4*)(masks + (size_t)n * HW);
    const float4* q0  = (const float4*)(quat  + ((size_t)sid * 4 + 0) * HW);
    const float4* q1  = (const float4*)(quat  + ((size_t)sid * 4 + 1) * HW);
    const float4* q2  = (const float4*)(quat  + ((size_t)sid * 4 + 2) * HW);
    const float4* q3  = (const float4*)(quat  + ((size_t)sid * 4 + 3) * HW);
    const float4* s0  = (const float4*)(scales + ((size_t)sid * 3 + 0) * HW);
    const float4* s1  = (const float4*)(scales + ((size_t)sid * 3 + 1) * HW);
    const float4* s2  = (const float4*)(scales + ((size_t)sid * 3 + 2) * HW);
    const float4* x0  = (const float4*)(xy    + ((size_t)sid * 2 + 0) * HW);
    const float4* x1  = (const float4*)(xy    + ((size_t)sid * 2 + 1) * HW);
    const float4* z0  = (const float4*)(z     + (size_t)sid * HW);
    float4* oxy0 = (float4*)(out + 512 + ((size_t)n * 2 + 0) * HW);
    float4* oxy1 = (float4*)(out + 512 + ((size_t)n * 2 + 1) * HW);

    float acc[NV];
#pragma unroll
    for (int v = 0; v < NV; ++v) acc[v] = 0.0f;

    for (int i = b * THREADS + tid; i < HW4; i += BPI * THREADS) {
        const float4 m = m4[i];

        // xy_masked (dense output)
        const float4 a0 = x0[i];
        const float4 a1 = x1[i];
        oxy0[i] = make_float4(m.x * a0.x, m.y * a0.y, m.z * a0.z, m.w * a0.w);
        oxy1[i] = make_float4(m.x * a1.x, m.y * a1.y, m.z * a1.z, m.w * a1.w);

        // reductions
        acc[0] += (m.x + m.y) + (m.z + m.w);
        float4 t;
        t = q0[i]; acc[1] += m.x*t.x + m.y*t.y + m.z*t.z + m.w*t.w;
        t = q1[i]; acc[2] += m.x*t.x + m.y*t.y + m.z*t.z + m.w*t.w;
        t = q2[i]; acc[3] += m.x*t.x + m.y*t.y + m.z*t.z + m.w*t.w;
        t = q3[i]; acc[4] += m.x*t.x + m.y*t.y + m.z*t.z + m.w*t.w;
        t = s0[i]; acc[5] += m.x*t.x + m.y*t.y + m.z*t.z + m.w*t.w;
        t = s1[i]; acc[6] += m.x*t.x + m.y*t.y + m.z*t.z + m.w*t.w;
        t = s2[i]; acc[7] += m.x*t.x + m.y*t.y + m.z*t.z + m.w*t.w;
        t = z0[i]; acc[8] += m.x*t.x + m.y*t.y + m.z*t.z + m.w*t.w;
    }

    // block reduction: wave64 shuffle, then cross-wave via LDS
    __shared__ float sred[4][NV];
    const int lane = tid & 63;
    const int wid  = tid >> 6;
#pragma unroll
    for (int v = 0; v < NV; ++v) {
        float val = acc[v];
#pragma unroll
        for (int off = 32; off > 0; off >>= 1)
            val += __shfl_down(val, off, 64);
        if (lane == 0) sred[wid][v] = val;
    }
    __syncthreads();
    if (tid < NV) {
        float s = sred[0][tid] + sred[1][tid] + sred[2][tid] + sred[3][tid];
        part[(size_t)blk * NV + tid] = s;
    }
}

// Finalize: 64 threads, one per instance. Sum BPI partials, compute means,
// L2-normalize q, exp(z-mean), write the 512 aggregate floats.
__global__ __launch_bounds__(64) void agg_final(
    const float* __restrict__ part,    // [NINST*BPI][NV]
    float*       __restrict__ out)
{
    const int n = threadIdx.x;
    if (n >= NINST) return;

    float s[NV];
#pragma unroll
    for (int v = 0; v < NV; ++v) s[v] = 0.0f;
    for (int b = 0; b < BPI; ++b) {
        const float* p = part + ((size_t)n * BPI + b) * NV;
#pragma unroll
        for (int v = 0; v < NV; ++v) s[v] += p[v];
    }

    const float inv = 1.0f / s[0];                 // 1 / mask_size
    const float q0 = s[1] * inv, q1 = s[2] * inv, q2 = s[3] * inv, q3 = s[4] * inv;
    const float norm = sqrtf(q0*q0 + q1*q1 + q2*q2 + q3*q3);
    const float d = fmaxf(norm, 1e-12f);
    out[n * 4 + 0] = q0 / d;
    out[n * 4 + 1] = q1 / d;
    out[n * 4 + 2] = q2 / d;
    out[n * 4 + 3] = q3 / d;

    out[256 + n * 3 + 0] = s[5] * inv;
    out[256 + n * 3 + 1] = s[6] * inv;
    out[256 + n * 3 + 2] = s[7] * inv;

    out[448 + n] = expf(s[8] * inv);
}

extern "C" void kernel_launch(void* const* d_in, const int* in_sizes, int n_in,
                              void* d_out, int out_size, void* d_ws, size_t ws_size,
                              hipStream_t stream) {
    const float* masks  = (const float*)d_in[0];   // [64,480,480]
    const int*   sids   = (const int*)d_in[1];     // [64]
    const float* quat   = (const float*)d_in[2];   // [8,4,480,480]
    const float* scales = (const float*)d_in[3];   // [8,3,480,480]
    const float* xy     = (const float*)d_in[4];   // [8,2,480,480]
    const float* z      = (const float*)d_in[5];   // [8,480,480]
    float* out  = (float*)d_out;
    float* part = (float*)d_ws;                    // NINST*BPI*NV floats = 73728 B

    agg_main<<<NINST * BPI, THREADS, 0, stream>>>(masks, sids, quat, scales, xy, z, out, part);
    agg_final<<<1, 64, 0, stream>>>(part, out);
}

// Round 2
// 245.556 us; speedup vs baseline: 1.0776x; 1.0776x over previous
//
#include <hip/hip_runtime.h>
#include <math.h>

// Problem constants (from reference): B=8, N_INST=64, H=W=480
#define HW      (480 * 480)     // 230400 pixels per plane
#define HW4     (HW / 4)        // 57600 float4 per plane
#define NINST   64
#define NB      8               // batch
#define NV      9               // reduced values: mask, q0..3, s0..2, z
#define THREADS 256
#define NCHUNK  (HW4 / THREADS) // 225 chunks per plane

// Grid = (NCHUNK, NB). Each block owns one 256-float4 chunk of one sample:
// load the sample's 10 shared planes for this chunk ONCE into registers,
// then loop over the instances belonging to this sample (uniform branch):
// mask load + xy_masked store + 9 masked-dot partials -> block reduce ->
// part[n][chunk][v]. Every (n,chunk) slot is written exactly once (by the
// block of sample sids[n]) so no ws init is needed.
__global__ __launch_bounds__(THREADS) void agg_main(
    const float* __restrict__ masks,   // [N,H,W]
    const int*   __restrict__ sids,    // [N]
    const float* __restrict__ quat,    // [B,4,H,W]
    const float* __restrict__ scales,  // [B,3,H,W]
    const float* __restrict__ xy,      // [B,2,H,W]
    const float* __restrict__ z,       // [B,H,W]
    float*       __restrict__ out,     // xy_masked lives at out+512
    float*       __restrict__ part)    // [NINST][NCHUNK][NV]
{
    const int c   = blockIdx.x;                    // chunk
    const int b   = blockIdx.y;                    // sample
    const int tid = threadIdx.x;
    const int i   = c * THREADS + tid;             // float4 index within a plane

    const float4* Q  = (const float4*)quat;
    const float4* S  = (const float4*)scales;
    const float4* X  = (const float4*)xy;
    const float4* Z  = (const float4*)z;
    const float4* M  = (const float4*)masks;
    float4*       O  = (float4*)(out + 512);

    // Shared planes for this (sample, chunk) -> registers (10 x float4)
    const size_t qb = (size_t)b * 4 * HW4 + i;
    const float4 vq0 = Q[qb + 0 * HW4];
    const float4 vq1 = Q[qb + 1 * HW4];
    const float4 vq2 = Q[qb + 2 * HW4];
    const float4 vq3 = Q[qb + 3 * HW4];
    const size_t sb = (size_t)b * 3 * HW4 + i;
    const float4 vs0 = S[sb + 0 * HW4];
    const float4 vs1 = S[sb + 1 * HW4];
    const float4 vs2 = S[sb + 2 * HW4];
    const size_t xb = (size_t)b * 2 * HW4 + i;
    const float4 vx0 = X[xb + 0 * HW4];
    const float4 vx1 = X[xb + 1 * HW4];
    const float4 vz  = Z[(size_t)b * HW4 + i];

    __shared__ float sred[4][NV];
    const int lane = tid & 63;
    const int wid  = tid >> 6;

    for (int n = 0; n < NINST; ++n) {
        if (sids[n] != b) continue;                // uniform (scalar) branch

        const float4 m = M[(size_t)n * HW4 + i];

        // dense masked xy output
        O[((size_t)n * 2 + 0) * HW4 + i] =
            make_float4(m.x * vx0.x, m.y * vx0.y, m.z * vx0.z, m.w * vx0.w);
        O[((size_t)n * 2 + 1) * HW4 + i] =
            make_float4(m.x * vx1.x, m.y * vx1.y, m.z * vx1.z, m.w * vx1.w);

        float vals[NV];
        vals[0] = (m.x + m.y) + (m.z + m.w);
        vals[1] = m.x*vq0.x + m.y*vq0.y + m.z*vq0.z + m.w*vq0.w;
        vals[2] = m.x*vq1.x + m.y*vq1.y + m.z*vq1.z + m.w*vq1.w;
        vals[3] = m.x*vq2.x + m.y*vq2.y + m.z*vq2.z + m.w*vq2.w;
        vals[4] = m.x*vq3.x + m.y*vq3.y + m.z*vq3.z + m.w*vq3.w;
        vals[5] = m.x*vs0.x + m.y*vs0.y + m.z*vs0.z + m.w*vs0.w;
        vals[6] = m.x*vs1.x + m.y*vs1.y + m.z*vs1.z + m.w*vs1.w;
        vals[7] = m.x*vs2.x + m.y*vs2.y + m.z*vs2.z + m.w*vs2.w;
        vals[8] = m.x*vz.x  + m.y*vz.y  + m.z*vz.z  + m.w*vz.w;

#pragma unroll
        for (int v = 0; v < NV; ++v) {
            float x = vals[v];
#pragma unroll
            for (int off = 32; off > 0; off >>= 1)
                x += __shfl_down(x, off, 64);
            if (lane == 0) sred[wid][v] = x;
        }
        __syncthreads();
        if (tid < NV)
            part[((size_t)n * NCHUNK + c) * NV + tid] =
                (sred[0][tid] + sred[1][tid]) + (sred[2][tid] + sred[3][tid]);
        __syncthreads();                            // sred reused next instance
    }
}

// Finalize: one block per instance; sum NCHUNK partials, compute means,
// L2-normalize q, exp(z mean), write the 512 aggregate floats.
__global__ __launch_bounds__(THREADS) void agg_final(
    const float* __restrict__ part,    // [NINST][NCHUNK][NV]
    float*       __restrict__ out)
{
    const int n   = blockIdx.x;
    const int tid = threadIdx.x;

    float vals[NV];
#pragma unroll
    for (int v = 0; v < NV; ++v) vals[v] = 0.0f;
    for (int c = tid; c < NCHUNK; c += THREADS) {
        const float* p = part + ((size_t)n * NCHUNK + c) * NV;
#pragma unroll
        for (int v = 0; v < NV; ++v) vals[v] += p[v];
    }

    __shared__ float sred[4][NV];
    const int lane = tid & 63;
    const int wid  = tid >> 6;
#pragma unroll
    for (int v = 0; v < NV; ++v) {
        float x = vals[v];
#pragma unroll
        for (int off = 32; off > 0; off >>= 1)
            x += __shfl_down(x, off, 64);
        if (lane == 0) sred[wid][v] = x;
    }
    __syncthreads();

    if (tid == 0) {
        float s[NV];
#pragma unroll
        for (int v = 0; v < NV; ++v)
            s[v] = (sred[0][v] + sred[1][v]) + (sred[2][v] + sred[3][v]);

        const float inv = 1.0f / s[0];             // 1 / mask_size
        const float q0 = s[1] * inv, q1 = s[2] * inv, q2 = s[3] * inv, q3 = s[4] * inv;
        const float norm = sqrtf(q0*q0 + q1*q1 + q2*q2 + q3*q3);
        const float d = fmaxf(norm, 1e-12f);
        out[n * 4 + 0] = q0 / d;
        out[n * 4 + 1] = q1 / d;
        out[n * 4 + 2] = q2 / d;
        out[n * 4 + 3] = q3 / d;

        out[256 + n * 3 + 0] = s[5] * inv;
        out[256 + n * 3 + 1] = s[6] * inv;
        out[256 + n * 3 + 2] = s[7] * inv;

        out[448 + n] = expf(s[8] * inv);
    }
}

extern "C" void kernel_launch(void* const* d_in, const int* in_sizes, int n_in,
                              void* d_out, int out_size, void* d_ws, size_t ws_size,
                              hipStream_t stream) {
    const float* masks  = (const float*)d_in[0];   // [64,480,480]
    const int*   sids   = (const int*)d_in[1];     // [64]
    const float* quat   = (const float*)d_in[2];   // [8,4,480,480]
    const float* scales = (const float*)d_in[3];   // [8,3,480,480]
    const float* xy     = (const float*)d_in[4];   // [8,2,480,480]
    const float* z      = (const float*)d_in[5];   // [8,480,480]
    float* out  = (float*)d_out;
    float* part = (float*)d_ws;                    // 64*225*9*4 B = 518400 B

    dim3 grid(NCHUNK, NB);
    agg_main<<<grid, THREADS, 0, stream>>>(masks, sids, quat, scales, xy, z, out, part);
    agg_final<<<NINST, THREADS, 0, stream>>>(part, out);
}